// Round 8
// baseline (728.070 us; speedup 1.0000x reference)
//
#include <hip/hip_runtime.h>

// ---------- sizes (hardcoded for this problem) ----------
#define BATCH 4
#define SEQ   4096
#define DMODEL 2048
#define NHEAD 16
#define DHEAD 128
#define MROWS (BATCH*SEQ)          // 16384
#define LC    64                   // scan chunk length (fused pass3 => 256 blocks)
#define NCH   (SEQ/LC)             // 64 chunks

typedef unsigned short ushort_t;
typedef __bf16 v8bf  __attribute__((ext_vector_type(8)));
typedef float  f32x16 __attribute__((ext_vector_type(16)));

__device__ __forceinline__ float b2f(ushort_t h) {
    return __uint_as_float(((unsigned)h) << 16);
}
__device__ __forceinline__ ushort_t f2b(float f) {
    unsigned u = __float_as_uint(f);
    return (ushort_t)((u + 0x7fffu + ((u >> 16) & 1u)) >> 16);
}

// ---------- cast fp32 -> bf16 (8 elem/thread, 16B loads+stores) ----------
__global__ void cast_f32_bf16(const float* __restrict__ in, ushort_t* __restrict__ out, int n) {
    int i = (blockIdx.x * blockDim.x + threadIdx.x) * 8;
    const int stride = gridDim.x * blockDim.x * 8;
    for (; i < n; i += stride) {
        float4 a = *(const float4*)(in + i);
        float4 b = *(const float4*)(in + i + 4);
        ushort_t o[8] = {f2b(a.x), f2b(a.y), f2b(a.z), f2b(a.w),
                         f2b(b.x), f2b(b.y), f2b(b.z), f2b(b.w)};
        *(uint4*)(out + i) = *(const uint4*)o;
    }
}

// 4 weight matrices in one launch (blockIdx.y selects)
__global__ void cast_weights(const float* __restrict__ w0, const float* __restrict__ w1,
                             const float* __restrict__ w2, const float* __restrict__ w3,
                             ushort_t* __restrict__ o0, ushort_t* __restrict__ o1,
                             ushort_t* __restrict__ o2, ushort_t* __restrict__ o3) {
    const int wsel = blockIdx.y;
    const float* src = wsel == 0 ? w0 : wsel == 1 ? w1 : wsel == 2 ? w2 : w3;
    ushort_t* dst    = wsel == 0 ? o0 : wsel == 1 ? o1 : wsel == 2 ? o2 : o3;
    const int n = DMODEL * DMODEL;
    int i = (blockIdx.x * blockDim.x + threadIdx.x) * 8;
    const int stride = gridDim.x * blockDim.x * 8;
    for (; i < n; i += stride) {
        float4 a = *(const float4*)(src + i);
        float4 b = *(const float4*)(src + i + 4);
        ushort_t o[8] = {f2b(a.x), f2b(a.y), f2b(a.z), f2b(a.w),
                         f2b(b.x), f2b(b.y), f2b(b.z), f2b(b.w)};
        *(uint4*)(dst + i) = *(const uint4*)o;
    }
}

// ======== 256x256 bf16 GEMM: 32x32x16 MFMA, conflict-free LDS, pipelined body ========
// C = A(MxK) * B(NxK)^T. 512 threads = 8 waves (2M x 4N), per-wave 128x64 out = 4x2
// tiles of 32x32. LDS 128 KiB: [2 buf][ A:256x64 | B:256x64 ] bf16 row-major, 128B rows.
// Swizzle: physical 16B-slot-in-row = logical_slot ^ (row & 7); dest linear, source
// pre-swizzled. Per K-tile: 24 ds_read_b128, 32 MFMA(32x32x16), vmcnt(2) + 2 barriers.
// Read beats: 32 lanes, rows 0..31, fixed logical slot -> phys spread = 8 slots x 4
// lanes = uniform over 32 banks (conflict-free minimum, verified r5 counters = 0).

#define GLL(src, dstoff) __builtin_amdgcn_global_load_lds( \
    (const __attribute__((address_space(1))) void*)(src), \
    (__attribute__((address_space(3))) void*)((char*)lds + (dstoff)), 16, 0, 0)

#define STG_A(buf, half, kt) do { \
    GLL(pA + ((half) * 128 +  0) * (size_t)K + (kt), (buf) * 65536 + (half) * 16384 + wid * 1024); \
    GLL(pA + ((half) * 128 + 64) * (size_t)K + (kt), (buf) * 65536 + (half) * 16384 + wid * 1024 + 8192); } while (0)
#define STG_B(buf, half, kt) do { \
    GLL(pB + ((half) * 128 +  0) * (size_t)K + (kt), (buf) * 65536 + 32768 + (half) * 16384 + wid * 1024); \
    GLL(pB + ((half) * 128 + 64) * (size_t)K + (kt), (buf) * 65536 + 32768 + (half) * 16384 + wid * 1024 + 8192); } while (0)

// one k-step (K=16): 4 A-frags + 2 B-frags (6 x ds_read_b128)
#define RD6(FA, FB, ks) do { \
    const int _sl = ((((ks) * 2 + khalf) ^ sx7)) * 8; \
    const ushort_t* _pa = lds + cb + aw + _sl; \
    FA[0] = *(const v8bf*)_pa;          FA[1] = *(const v8bf*)(_pa + 2048); \
    FA[2] = *(const v8bf*)(_pa + 4096); FA[3] = *(const v8bf*)(_pa + 6144); \
    const ushort_t* _pb = lds + cb + bw + _sl; \
    FB[0] = *(const v8bf*)_pb;          FB[1] = *(const v8bf*)(_pb + 2048); \
} while (0)

#define VMW(n) asm volatile("s_waitcnt vmcnt(" #n ")" ::: "memory")
#define BAR()  __builtin_amdgcn_s_barrier()

// prioritized 8-MFMA cluster (compiler inserts counted lgkmcnt before first use)
#define MM8(FA, FB) do { \
    __builtin_amdgcn_s_setprio(1); \
    _Pragma("unroll") \
    for (int _m = 0; _m < 4; ++_m) \
        _Pragma("unroll") \
        for (int _n = 0; _n < 2; ++_n) \
            acc[_m][_n] = __builtin_amdgcn_mfma_f32_32x32x16_bf16( \
                FA[_m], FB[_n], acc[_m][_n], 0, 0, 0); \
    __builtin_amdgcn_s_setprio(0); \
} while (0)

template<int N, int EPI>
__global__ __launch_bounds__(512, 2) void gemm8(const ushort_t* __restrict__ A,
                                                const ushort_t* __restrict__ Bm,
                                                ushort_t* __restrict__ o0,
                                                ushort_t* __restrict__ o1,
                                                ushort_t* __restrict__ o2,
                                                float* __restrict__ of) {
    constexpr int K  = DMODEL;
    constexpr int NT = K / 64;           // 32 K-tiles
    constexpr int NBN = N / 256;
    constexpr int NWG = (MROWS / 256) * NBN;
    extern __shared__ ushort_t lds[];    // 65536 ushorts = 128 KiB

    // XCD-bijective swizzle (NWG % 8 == 0 for both instantiations)
    int wg = blockIdx.x;
    wg = (wg & 7) * (NWG / 8) + (wg >> 3);
    const int tm = (wg / NBN) * 256;
    const int tn = (wg % NBN) * 256;

    const int tid  = threadIdx.x;
    const int lane = tid & 63;
    const int wid  = tid >> 6;           // 8 waves
    const int wr   = wid >> 2;           // 0..1 (M half)
    const int wc   = wid & 3;            // 0..3 (N quarter)

    // ---- staging source base (per-lane, pre-swizzled; dest stays linear) ----
    const int rs = wid * 8 + (lane >> 3);
    const int cs = ((lane & 7) ^ ((lane >> 3) & 7)) * 8;
    const ushort_t* pA = A  + (size_t)(tm + rs) * K + cs;
    const ushort_t* pB = Bm + (size_t)(tn + rs) * K + cs;

    // ---- 32x32x16 fragment addressing: row/col = lane&31, k = (lane>>5)*8 + j ----
    const int r31   = lane & 31;
    const int khalf = lane >> 5;
    const int sx7   = r31 & 7;
    const int aw = (wr * 128 + r31) * 64;          // + m*2048 per m-tile
    const int bw = 16384 + (wc * 64 + r31) * 64;   // + n*2048 per n-tile

    f32x16 acc[4][2] = {};
    v8bf Ae[4], Ao[4];
    v8bf Be[2], Bo[2];

    // ---- prologue: stage tile 0 fully into buf0 (8 loads), no wait yet ----
    STG_A(0, 0, 0); STG_A(0, 1, 0); STG_B(0, 0, 0); STG_B(0, 1, 0);

    // ---- main loop: 4 k-steps per K-tile; vmcnt(2) + 2 barriers per K-tile ----
    for (int t = 0; t < NT - 1; ++t) {
        const int cur = t & 1, nxt = cur ^ 1;
        const int ktn = (t + 1) * 64;
        const int cb = cur * 32768;
        STG_A(nxt, 0, ktn);          // ledger: 8 old + 2 new
        VMW(2);                      // retire tile t's 8 loads
        BAR();
        RD6(Ae, Be, 0);
        RD6(Ao, Bo, 1);
        MM8(Ae, Be);                 // ks0
        STG_A(nxt, 1, ktn);
        RD6(Ae, Be, 2);
        MM8(Ao, Bo);                 // ks1
        STG_B(nxt, 0, ktn);
        RD6(Ao, Bo, 3);
        MM8(Ae, Be);                 // ks2
        STG_B(nxt, 1, ktn);
        MM8(Ao, Bo);                 // ks3
        BAR();                       // anti-overwrite fence
    }
    // ---- peeled last tile: no staging; full drain ----
    {
        const int cb = ((NT - 1) & 1) * 32768;
        VMW(0);
        BAR();
        RD6(Ae, Be, 0);
        RD6(Ao, Bo, 1);
        MM8(Ae, Be);
        RD6(Ae, Be, 2);
        MM8(Ao, Bo);
        RD6(Ao, Bo, 3);
        MM8(Ae, Be);
        MM8(Ao, Bo);
    }

    // ---- epilogue: C/D col=lane&31, row=(reg&3)+8*(reg>>2)+4*(lane>>5) ----
    if constexpr (EPI == 0) {
        ushort_t* out = (tn < 2048) ? o0 : (tn < 4096 ? o1 : o2);
        const int nc0 = tn & 2047;
#pragma unroll
        for (int m = 0; m < 4; ++m) {
            const int r0 = tm + wr * 128 + m * 32 + khalf * 4;
#pragma unroll
            for (int n = 0; n < 2; ++n) {
                const int c = nc0 + wc * 64 + n * 32 + r31;
#pragma unroll
                for (int reg = 0; reg < 16; ++reg) {
                    const int row = r0 + (reg & 3) + 8 * (reg >> 2);
                    out[(size_t)row * 2048 + c] = f2b(acc[m][n][reg]);
                }
            }
        }
    } else {
#pragma unroll
        for (int m = 0; m < 4; ++m) {
            const int r0 = tm + wr * 128 + m * 32 + khalf * 4;
#pragma unroll
            for (int n = 0; n < 2; ++n) {
                const int c = tn + wc * 64 + n * 32 + r31;
#pragma unroll
                for (int reg = 0; reg < 16; ++reg) {
                    const int row = r0 + (reg & 3) + 8 * (reg >> 2);
                    of[(size_t)row * N + c] = acc[m][n][reg];
                }
            }
        }
    }
}

// ---------- retention scan (state_t = lam*state_{t-1} + v_t), chunked ----------
// pass1: per-chunk (LC=64) local scan final -> cf[b][h][chunk][dh]
__global__ void scan_pass1(const ushort_t* __restrict__ v, const float* __restrict__ beta,
                           float* __restrict__ cf) {
    const int chunk = blockIdx.x, h = blockIdx.y, b = blockIdx.z;
    const int dh = threadIdx.x;   // 128
    const float lam = 1.f / (1.f + __expf(-beta[h]));
    size_t idx = ((size_t)(b * SEQ + chunk * LC) * NHEAD + h) * DHEAD + dh;
    float s = 0.f;
#pragma unroll 4
    for (int l = 0; l < LC; ++l) {
        s = fmaf(s, lam, b2f(v[idx]));
        idx += DMODEL;
    }
    cf[(((size_t)(b * NHEAD + h) * NCH) + chunk) * DHEAD + dh] = s;
}

// pass2: in-place exclusive scan over chunks
__global__ void scan_pass2(float* __restrict__ cf, const float* __restrict__ beta) {
    const int t = blockIdx.x * blockDim.x + threadIdx.x;   // B*H*Dh = 8192
    const int dh = t & 127;
    const int bh = t >> 7;          // b*16 + h
    const int h = bh & 15;
    const float lam = 1.f / (1.f + __expf(-beta[h]));
    float lamLc = lam;
#pragma unroll
    for (int i = 0; i < 6; ++i) lamLc *= lamLc;   // lam^64
    float carry = 0.f;
    for (int c = 0; c < NCH; ++c) {
        const size_t i = ((size_t)bh * NCH + c) * DHEAD + dh;
        const float val = cf[i];
        cf[i] = carry;
        carry = fmaf(carry, lamLc, val);
    }
}

// ---- fused pass3: scan + y=q*state + rowwise LayerNorm + SiLU gate -> t (bf16) ----
// grid (NCH, BATCH) = 256 blocks x 512 threads; thread handles 4 channels of one head.
// t may alias g element-for-element (g[idx] read before t[idx] written by same thread).
__global__ __launch_bounds__(512) void scan3_ln_gate(const ushort_t* __restrict__ v,
                                                     const ushort_t* __restrict__ q,
                                                     const ushort_t* g,
                                                     const float* __restrict__ beta,
                                                     const float* __restrict__ cf,
                                                     const float* __restrict__ lnw,
                                                     const float* __restrict__ lnb,
                                                     ushort_t* t) {
    const int chunk = blockIdx.x;      // 64
    const int b     = blockIdx.y;      // 4
    const int tid   = threadIdx.x;     // 512
    const int h     = tid >> 5;        // 16 heads, 32 threads each
    const int col   = (h << 7) + ((tid & 31) << 2);   // h*128 + lane4*4
    const float lam = 1.f / (1.f + __expf(-beta[h]));

    float s0, s1, s2, s3;
    {
        const float* c0 = cf + ((size_t)(b * NHEAD + h) * NCH + chunk) * DHEAD + ((tid & 31) << 2);
        s0 = c0[0]; s1 = c0[1]; s2 = c0[2]; s3 = c0[3];
    }
    const float w0 = lnw[col], w1 = lnw[col + 1], w2 = lnw[col + 2], w3 = lnw[col + 3];
    const float e0 = lnb[col], e1 = lnb[col + 1], e2 = lnb[col + 2], e3 = lnb[col + 3];

    __shared__ float red[16];
    size_t idx = (size_t)(b * SEQ + chunk * LC) * DMODEL + col;

    for (int l = 0; l < LC; ++l) {
        const uint2 vv = *(const uint2*)(v + idx);
        s0 = fmaf(s0, lam, b2f((ushort_t)(vv.x & 0xffff)));
        s1 = fmaf(s1, lam, b2f((ushort_t)(vv.x >> 16)));
        s2 = fmaf(s2, lam, b2f((ushort_t)(vv.y & 0xffff)));
        s3 = fmaf(s3, lam, b2f((ushort_t)(vv.y >> 16)));
        const uint2 qv = *(const uint2*)(q + idx);
        const float y0 = b2f((ushort_t)(qv.x & 0xffff)) * s0;
        const float y1 = b2f((ushort_t)(qv.x >> 16)) * s1;
        const float y2 = b2f((ushort_t)(qv.y & 0xffff)) * s2;
        const float y3 = b2f((ushort_t)(qv.y >> 16)) * s3;

        float ps  = y0 + y1 + y2 + y3;
        float pss = y0 * y0 + y1 * y1 + y2 * y2 + y3 * y3;
#pragma unroll
        for (int o = 32; o > 0; o >>= 1) {
            ps  += __shfl_down(ps, o);
            pss += __shfl_down(pss, o);
        }
        const int wv = tid >> 6;
        if ((tid & 63) == 0) { red[wv] = ps; red[8 + wv] = pss; }
        __syncthreads();
        float S = 0.f, SS = 0.f;
#pragma unroll
        for (int k = 0; k < 8; ++k) { S += red[k]; SS += red[8 + k]; }

        const float mu  = S * (1.f / DMODEL);
        const float var = SS * (1.f / DMODEL) - mu * mu;
        const float rsr = rsqrtf(var + 1e-5f);

        const uint2 gv = *(const uint2*)(g + idx);
        const float g0 = b2f((ushort_t)(gv.x & 0xffff));
        const float g1 = b2f((ushort_t)(gv.x >> 16));
        const float g2 = b2f((ushort_t)(gv.y & 0xffff));
        const float g3 = b2f((ushort_t)(gv.y >> 16));

        ushort_t o[4];
        o[0] = f2b(((y0 - mu) * rsr * w0 + e0) * (g0 / (1.f + __expf(-g0))));
        o[1] = f2b(((y1 - mu) * rsr * w1 + e1) * (g1 / (1.f + __expf(-g1))));
        o[2] = f2b(((y2 - mu) * rsr * w2 + e2) * (g2 / (1.f + __expf(-g2))));
        o[3] = f2b(((y3 - mu) * rsr * w3 + e3) * (g3 / (1.f + __expf(-g3))));
        *(uint2*)(t + idx) = *(const uint2*)o;

        __syncthreads();   // protect red[] before next iteration's writes
        idx += DMODEL;
    }
}

// ---------- workspace layout (bytes) — TOTAL 160 MiB ----------
// cf overlays the xb slab (xb dead after the qvg GEMM; fused pass3 removed y).
#define OFF_XB  ((size_t)0)                         // 64 MiB (xb; cf after qvg)
#define OFF_WC  (OFF_XB + (size_t)MROWS*DMODEL*2)   // 24 MiB
#define OFF_WOB (OFF_WC + (size_t)3*DMODEL*DMODEL*2)// 8 MiB
#define OFF_G   (OFF_WOB + (size_t)DMODEL*DMODEL*2) // 64 MiB (g, later t)
#define OFF_END (OFF_G + (size_t)MROWS*DMODEL*2)

extern "C" void kernel_launch(void* const* d_in, const int* in_sizes, int n_in,
                              void* d_out, int out_size, void* d_ws, size_t ws_size,
                              hipStream_t stream) {
    if (ws_size < OFF_END) return;  // refuse to run rather than corrupt adjacent memory

    const float* x    = (const float*)d_in[0];
    const float* Wq   = (const float*)d_in[1];
    const float* Wv   = (const float*)d_in[2];
    const float* Wg   = (const float*)d_in[3];
    const float* Wo   = (const float*)d_in[4];
    const float* beta = (const float*)d_in[5];
    const float* lnw  = (const float*)d_in[6];
    const float* lnb  = (const float*)d_in[7];

    char* ws = (char*)d_ws;
    ushort_t* xb  = (ushort_t*)(ws + OFF_XB);
    ushort_t* Wc  = (ushort_t*)(ws + OFF_WC);
    ushort_t* Wob = (ushort_t*)(ws + OFF_WOB);
    ushort_t* g   = (ushort_t*)(ws + OFF_G);
    float*    cf  = (float*)(ws + OFF_XB);   // overlays xb (dead after qvg GEMM)

    ushort_t* q = (ushort_t*)d_out;
    ushort_t* v = q + (size_t)MROWS * DMODEL;
    ushort_t* t = g;    // g slab reused by fused pass3 (element-wise aliasing)

    const int DD = DMODEL * DMODEL;

    // allow 128 KiB dynamic LDS (idempotent; return value intentionally ignored)
    (void)hipFuncSetAttribute((const void*)gemm8<3 * DMODEL, 0>,
                              hipFuncAttributeMaxDynamicSharedMemorySize, 131072);
    (void)hipFuncSetAttribute((const void*)gemm8<DMODEL, 1>,
                              hipFuncAttributeMaxDynamicSharedMemorySize, 131072);

    cast_f32_bf16<<<2048, 256, 0, stream>>>(x, xb, MROWS * DMODEL);
    cast_weights<<<dim3(256, 4), 256, 0, stream>>>(Wq, Wv, Wg, Wo,
                                                   Wc, Wc + DD, Wc + 2 * DD, Wob);

    // q,v,g = x @ [Wq;Wv;Wg]^T   (M=16384, N=6144, K=2048)
    gemm8<3 * DMODEL, 0><<<(MROWS / 256) * (3 * DMODEL / 256), 512, 131072, stream>>>(
        xb, Wc, q, v, g, nullptr);

    scan_pass1<<<dim3(NCH, NHEAD, BATCH), DHEAD, 0, stream>>>(v, beta, cf);
    scan_pass2<<<(BATCH * NHEAD * DHEAD) / 256, 256, 0, stream>>>(cf, beta);
    scan3_ln_gate<<<dim3(NCH, BATCH), 512, 0, stream>>>(v, q, g, beta, cf, lnw, lnb, t);

    // out = t @ Wo^T  (M=16384, N=2048, K=2048), fp32 output
    gemm8<DMODEL, 1><<<(MROWS / 256) * (DMODEL / 256), 512, 131072, stream>>>(
        t, Wob, nullptr, nullptr, nullptr, (float*)d_out);
}

// Round 9
// 672.365 us; speedup vs baseline: 1.0828x; 1.0828x over previous
//
#include <hip/hip_runtime.h>

// ---------- sizes (hardcoded for this problem) ----------
#define BATCH 4
#define SEQ   4096
#define DMODEL 2048
#define NHEAD 16
#define DHEAD 128
#define MROWS (BATCH*SEQ)          // 16384
#define LC    64                   // scan chunk length (fused pass3 => 256 blocks)
#define NCH   (SEQ/LC)             // 64 chunks

typedef unsigned short ushort_t;
typedef __bf16 v8bf __attribute__((ext_vector_type(8)));
typedef float  f32x4 __attribute__((ext_vector_type(4)));

__device__ __forceinline__ float b2f(ushort_t h) {
    return __uint_as_float(((unsigned)h) << 16);
}
__device__ __forceinline__ ushort_t f2b(float f) {
    unsigned u = __float_as_uint(f);
    return (ushort_t)((u + 0x7fffu + ((u >> 16) & 1u)) >> 16);
}

// ---------- cast fp32 -> bf16 (8 elem/thread, 16B loads+stores) ----------
__global__ void cast_f32_bf16(const float* __restrict__ in, ushort_t* __restrict__ out, int n) {
    int i = (blockIdx.x * blockDim.x + threadIdx.x) * 8;
    const int stride = gridDim.x * blockDim.x * 8;
    for (; i < n; i += stride) {
        float4 a = *(const float4*)(in + i);
        float4 b = *(const float4*)(in + i + 4);
        ushort_t o[8] = {f2b(a.x), f2b(a.y), f2b(a.z), f2b(a.w),
                         f2b(b.x), f2b(b.y), f2b(b.z), f2b(b.w)};
        *(uint4*)(out + i) = *(const uint4*)o;
    }
}

// 4 weight matrices in one launch (blockIdx.y selects)
__global__ void cast_weights(const float* __restrict__ w0, const float* __restrict__ w1,
                             const float* __restrict__ w2, const float* __restrict__ w3,
                             ushort_t* __restrict__ o0, ushort_t* __restrict__ o1,
                             ushort_t* __restrict__ o2, ushort_t* __restrict__ o3) {
    const int wsel = blockIdx.y;
    const float* src = wsel == 0 ? w0 : wsel == 1 ? w1 : wsel == 2 ? w2 : w3;
    ushort_t* dst    = wsel == 0 ? o0 : wsel == 1 ? o1 : wsel == 2 ? o2 : o3;
    const int n = DMODEL * DMODEL;
    int i = (blockIdx.x * blockDim.x + threadIdx.x) * 8;
    const int stride = gridDim.x * blockDim.x * 8;
    for (; i < n; i += stride) {
        float4 a = *(const float4*)(src + i);
        float4 b = *(const float4*)(src + i + 4);
        ushort_t o[8] = {f2b(a.x), f2b(a.y), f2b(a.z), f2b(a.w),
                         f2b(b.x), f2b(b.y), f2b(b.z), f2b(b.w)};
        *(uint4*)(dst + i) = *(const uint4*)o;
    }
}

// ======== 256x256 bf16 GEMM: 16x16x32 MFMA, conflict-free LDS, pipelined body ========
// (round-7 verified: 357us qvg, MfmaUtil 54%, SQ_LDS_BANK_CONFLICT = 0)
// NOTE (r8 lesson): do NOT switch to 32x32x16 fragments here — their A-read needs 32
// lanes x same 16B-slot across 32 rows; a 128B row has only 8 slots -> unavoidable
// 4-way bank conflict (measured 3.78e7). 16x16x32 reads 16 rows x 4 slots = free 2-way.
// C = A(MxK) * B(NxK)^T. 512 threads = 8 waves (2M x 4N), per-wave 128x64 out.
// LDS 128 KiB: [2 buf][ A:256x64 | B:256x64 ] bf16, row-major, 128B rows.
// Swizzle: physical 16B-slot-in-row = logical_slot ^ (row & 7); dest linear, source
// pre-swizzled (involution both sides). Sync: 2 barriers + 1 counted vmcnt(2) per K-tile;
// no manual lgkm drains — named frag sets let the compiler emit counted lgkmcnt so
// cluster p's MFMA hides cluster p+1's ds_read latency.

#define GLL(src, dstoff) __builtin_amdgcn_global_load_lds( \
    (const __attribute__((address_space(1))) void*)(src), \
    (__attribute__((address_space(3))) void*)((char*)lds + (dstoff)), 16, 0, 0)

#define STG_A(buf, half, kt) do { \
    GLL(pA + ((half) * 128 +  0) * (size_t)K + (kt), (buf) * 65536 + (half) * 16384 + wid * 1024); \
    GLL(pA + ((half) * 128 + 64) * (size_t)K + (kt), (buf) * 65536 + (half) * 16384 + wid * 1024 + 8192); } while (0)
#define STG_B(buf, half, kt) do { \
    GLL(pB + ((half) * 128 +  0) * (size_t)K + (kt), (buf) * 65536 + 32768 + (half) * 16384 + wid * 1024); \
    GLL(pB + ((half) * 128 + 64) * (size_t)K + (kt), (buf) * 65536 + 32768 + (half) * 16384 + wid * 1024 + 8192); } while (0)

// 4 ds_read_b128 into a named v8bf[4] set (offsets in ushort units; +1024 = 16 rows)
#define DSRD4(dst, off) do { \
    const ushort_t* _p = lds + (off); \
    dst[0] = *(const v8bf*)_p;          dst[1] = *(const v8bf*)(_p + 1024); \
    dst[2] = *(const v8bf*)(_p + 2048); dst[3] = *(const v8bf*)(_p + 3072); } while (0)

#define VMW(n) asm volatile("s_waitcnt vmcnt(" #n ")" ::: "memory")
#define BAR()  __builtin_amdgcn_s_barrier()

// prioritized 16-MFMA cluster; compiler inserts the (counted) lgkmcnt before first use
#define MM(mh, va, vb) do { \
    __builtin_amdgcn_s_setprio(1); \
    _Pragma("unroll") \
    for (int _m = 0; _m < 4; ++_m) \
        _Pragma("unroll") \
        for (int _n = 0; _n < 4; ++_n) \
            acc[(mh) * 4 + _m][_n] = __builtin_amdgcn_mfma_f32_16x16x32_bf16( \
                va[_m], vb[_n], acc[(mh) * 4 + _m][_n], 0, 0, 0); \
    __builtin_amdgcn_s_setprio(0); \
} while (0)

template<int N, int EPI>
__global__ __launch_bounds__(512, 2) void gemm8(const ushort_t* __restrict__ A,
                                                const ushort_t* __restrict__ Bm,
                                                ushort_t* __restrict__ o0,
                                                ushort_t* __restrict__ o1,
                                                ushort_t* __restrict__ o2,
                                                float* __restrict__ of) {
    constexpr int K  = DMODEL;
    constexpr int NT = K / 64;           // 32 K-tiles
    constexpr int NBN = N / 256;
    constexpr int NWG = (MROWS / 256) * NBN;
    extern __shared__ ushort_t lds[];    // 65536 ushorts = 128 KiB

    // XCD-bijective swizzle (NWG % 8 == 0 for both instantiations)
    int wg = blockIdx.x;
    wg = (wg & 7) * (NWG / 8) + (wg >> 3);
    const int tm = (wg / NBN) * 256;
    const int tn = (wg % NBN) * 256;

    const int tid  = threadIdx.x;
    const int lane = tid & 63;
    const int wid  = tid >> 6;           // 8 waves
    const int wr   = wid >> 2;           // 0..1 (M half)
    const int wc   = wid & 3;            // 0..3 (N quarter)

    // ---- staging source base (per-lane, pre-swizzled; dest stays linear) ----
    // dest row = half*128 + j*64 + wid*8 + (lane>>3); phys slot-in-row = lane&7
    // -> logical slot = (lane&7) ^ ((lane>>3)&7)
    const int rs = wid * 8 + (lane >> 3);
    const int cs = ((lane & 7) ^ ((lane >> 3) & 7)) * 8;
    const ushort_t* pA = A  + (size_t)(tm + rs) * K + cs;
    const ushort_t* pB = Bm + (size_t)(tn + rs) * K + cs;

    // ---- fragment ds_read bases (ushort units) ----
    // logical slot = kk*4 + q (q = lane>>4); physical = logical ^ (l4 & 7)
    const int q  = lane >> 4;
    const int l4 = lane & 15;
    const int sx = l4 & 7;
    const int abase0 = (wr * 128 + l4) * 64 + ((q ^ sx)) * 8;
    const int abase1 = (wr * 128 + l4) * 64 + (((4 + q) ^ sx)) * 8;
    const int bbase0 = 16384 + (wc * 64 + l4) * 64 + ((q ^ sx)) * 8;
    const int bbase1 = 16384 + (wc * 64 + l4) * 64 + (((4 + q) ^ sx)) * 8;

    f32x4 acc[8][4] = {};
    v8bf a00[4], a10[4], a01[4], a11[4], b0[4], b1[4];

    // ---- prologue: stage tile 0 fully into buf0 (8 loads), no wait yet ----
    STG_A(0, 0, 0); STG_A(0, 1, 0); STG_B(0, 0, 0); STG_B(0, 1, 0);

    // ---- main loop: pipelined K-tile body; vmcnt(2) + 2 barriers per K-tile ----
    for (int t = 0; t < NT - 1; ++t) {
        const int cur = t & 1, nxt = cur ^ 1;
        const int ktn = (t + 1) * 64;
        const int cb = cur * 32768;
        // staged-before-wait keeps the ledger: 8 old + 2 new -> vmcnt(2) retires the 8
        STG_A(nxt, 0, ktn);
        VMW(2);
        BAR();
        // issue reads ahead; clusters consume in order (compiler emits counted lgkmcnt)
        DSRD4(a00, cb + abase0);          // mh0 kk0
        DSRD4(b0,  cb + bbase0);          // kk0
        DSRD4(a10, cb + abase0 + 4096);   // mh1 kk0
        MM(0, a00, b0);
        STG_A(nxt, 1, ktn);
        DSRD4(a01, cb + abase1);          // mh0 kk1
        DSRD4(b1,  cb + bbase1);          // kk1
        MM(1, a10, b0);
        STG_B(nxt, 0, ktn);
        DSRD4(a11, cb + abase1 + 4096);   // mh1 kk1
        MM(0, a01, b1);
        STG_B(nxt, 1, ktn);
        MM(1, a11, b1);
        BAR();   // anti-overwrite fence (all reads consumed -> lgkmcnt drained by MFMA waits)
    }
    // ---- peeled last tile: no staging; full drain ----
    {
        const int cb = ((NT - 1) & 1) * 32768;
        VMW(0);
        BAR();
        DSRD4(a00, cb + abase0);
        DSRD4(b0,  cb + bbase0);
        DSRD4(a10, cb + abase0 + 4096);
        MM(0, a00, b0);
        DSRD4(a01, cb + abase1);
        DSRD4(b1,  cb + bbase1);
        MM(1, a10, b0);
        DSRD4(a11, cb + abase1 + 4096);
        MM(0, a01, b1);
        MM(1, a11, b1);
    }

    // ---- epilogue: C/D layout col=lane&15, row=(lane>>4)*4+j ----
    const int cr = (lane >> 4) * 4;
    const int cc = lane & 15;
    if constexpr (EPI == 0) {
        ushort_t* out = (tn < 2048) ? o0 : (tn < 4096 ? o1 : o2);
        const int nc0 = tn & 2047;
#pragma unroll
        for (int m = 0; m < 8; ++m) {
            const int r0 = tm + wr * 128 + m * 16 + cr;
#pragma unroll
            for (int n = 0; n < 4; ++n) {
                const int c = nc0 + wc * 64 + n * 16 + cc;
#pragma unroll
                for (int j = 0; j < 4; ++j)
                    out[(size_t)(r0 + j) * 2048 + c] = f2b(acc[m][n][j]);
            }
        }
    } else {
#pragma unroll
        for (int m = 0; m < 8; ++m) {
            const int r0 = tm + wr * 128 + m * 16 + cr;
#pragma unroll
            for (int n = 0; n < 4; ++n) {
                const int c = tn + wc * 64 + n * 16 + cc;
#pragma unroll
                for (int j = 0; j < 4; ++j)
                    of[(size_t)(r0 + j) * N + c] = acc[m][n][j];
            }
        }
    }
}

// ---------- retention scan (state_t = lam*state_{t-1} + v_t), chunked ----------
// pass1: per-chunk (LC=64) local scan final -> cf[b][h][chunk][dh]
__global__ void scan_pass1(const ushort_t* __restrict__ v, const float* __restrict__ beta,
                           float* __restrict__ cf) {
    const int chunk = blockIdx.x, h = blockIdx.y, b = blockIdx.z;
    const int dh = threadIdx.x;   // 128
    const float lam = 1.f / (1.f + __expf(-beta[h]));
    size_t idx = ((size_t)(b * SEQ + chunk * LC) * NHEAD + h) * DHEAD + dh;
    float s = 0.f;
#pragma unroll 4
    for (int l = 0; l < LC; ++l) {
        s = fmaf(s, lam, b2f(v[idx]));
        idx += DMODEL;
    }
    cf[(((size_t)(b * NHEAD + h) * NCH) + chunk) * DHEAD + dh] = s;
}

// pass2: in-place exclusive scan over chunks
__global__ void scan_pass2(float* __restrict__ cf, const float* __restrict__ beta) {
    const int t = blockIdx.x * blockDim.x + threadIdx.x;   // B*H*Dh = 8192
    const int dh = t & 127;
    const int bh = t >> 7;          // b*16 + h
    const int h = bh & 15;
    const float lam = 1.f / (1.f + __expf(-beta[h]));
    float lamLc = lam;
#pragma unroll
    for (int i = 0; i < 6; ++i) lamLc *= lamLc;   // lam^64
    float carry = 0.f;
    for (int c = 0; c < NCH; ++c) {
        const size_t i = ((size_t)bh * NCH + c) * DHEAD + dh;
        const float val = cf[i];
        cf[i] = carry;
        carry = fmaf(carry, lamLc, val);
    }
}

// ---- fused pass3: scan + y=q*state + rowwise LayerNorm + SiLU gate -> t (bf16) ----
// grid (NCH, BATCH) = 256 blocks x 512 threads; thread handles 4 channels of one head.
// t may alias g element-for-element (g[idx] read before t[idx] written by same thread).
__global__ __launch_bounds__(512) void scan3_ln_gate(const ushort_t* __restrict__ v,
                                                     const ushort_t* __restrict__ q,
                                                     const ushort_t* g,
                                                     const float* __restrict__ beta,
                                                     const float* __restrict__ cf,
                                                     const float* __restrict__ lnw,
                                                     const float* __restrict__ lnb,
                                                     ushort_t* t) {
    const int chunk = blockIdx.x;      // 64
    const int b     = blockIdx.y;      // 4
    const int tid   = threadIdx.x;     // 512
    const int h     = tid >> 5;        // 16 heads, 32 threads each
    const int col   = (h << 7) + ((tid & 31) << 2);   // h*128 + lane4*4
    const float lam = 1.f / (1.f + __expf(-beta[h]));

    float s0, s1, s2, s3;
    {
        const float* c0 = cf + ((size_t)(b * NHEAD + h) * NCH + chunk) * DHEAD + ((tid & 31) << 2);
        s0 = c0[0]; s1 = c0[1]; s2 = c0[2]; s3 = c0[3];
    }
    const float w0 = lnw[col], w1 = lnw[col + 1], w2 = lnw[col + 2], w3 = lnw[col + 3];
    const float e0 = lnb[col], e1 = lnb[col + 1], e2 = lnb[col + 2], e3 = lnb[col + 3];

    __shared__ float red[16];
    size_t idx = (size_t)(b * SEQ + chunk * LC) * DMODEL + col;

    for (int l = 0; l < LC; ++l) {
        const uint2 vv = *(const uint2*)(v + idx);
        s0 = fmaf(s0, lam, b2f((ushort_t)(vv.x & 0xffff)));
        s1 = fmaf(s1, lam, b2f((ushort_t)(vv.x >> 16)));
        s2 = fmaf(s2, lam, b2f((ushort_t)(vv.y & 0xffff)));
        s3 = fmaf(s3, lam, b2f((ushort_t)(vv.y >> 16)));
        const uint2 qv = *(const uint2*)(q + idx);
        const float y0 = b2f((ushort_t)(qv.x & 0xffff)) * s0;
        const float y1 = b2f((ushort_t)(qv.x >> 16)) * s1;
        const float y2 = b2f((ushort_t)(qv.y & 0xffff)) * s2;
        const float y3 = b2f((ushort_t)(qv.y >> 16)) * s3;

        float ps  = y0 + y1 + y2 + y3;
        float pss = y0 * y0 + y1 * y1 + y2 * y2 + y3 * y3;
#pragma unroll
        for (int o = 32; o > 0; o >>= 1) {
            ps  += __shfl_down(ps, o);
            pss += __shfl_down(pss, o);
        }
        const int wv = tid >> 6;
        if ((tid & 63) == 0) { red[wv] = ps; red[8 + wv] = pss; }
        __syncthreads();
        float S = 0.f, SS = 0.f;
#pragma unroll
        for (int k = 0; k < 8; ++k) { S += red[k]; SS += red[8 + k]; }

        const float mu  = S * (1.f / DMODEL);
        const float var = SS * (1.f / DMODEL) - mu * mu;
        const float rsr = rsqrtf(var + 1e-5f);

        const uint2 gv = *(const uint2*)(g + idx);
        const float g0 = b2f((ushort_t)(gv.x & 0xffff));
        const float g1 = b2f((ushort_t)(gv.x >> 16));
        const float g2 = b2f((ushort_t)(gv.y & 0xffff));
        const float g3 = b2f((ushort_t)(gv.y >> 16));

        ushort_t o[4];
        o[0] = f2b(((y0 - mu) * rsr * w0 + e0) * (g0 / (1.f + __expf(-g0))));
        o[1] = f2b(((y1 - mu) * rsr * w1 + e1) * (g1 / (1.f + __expf(-g1))));
        o[2] = f2b(((y2 - mu) * rsr * w2 + e2) * (g2 / (1.f + __expf(-g2))));
        o[3] = f2b(((y3 - mu) * rsr * w3 + e3) * (g3 / (1.f + __expf(-g3))));
        *(uint2*)(t + idx) = *(const uint2*)o;

        __syncthreads();   // protect red[] before next iteration's writes
        idx += DMODEL;
    }
}

// ---------- workspace layout (bytes) — TOTAL 160 MiB ----------
// cf overlays the xb slab (xb dead after the qvg GEMM; fused pass3 removed y).
#define OFF_XB  ((size_t)0)                         // 64 MiB (xb; cf after qvg)
#define OFF_WC  (OFF_XB + (size_t)MROWS*DMODEL*2)   // 24 MiB
#define OFF_WOB (OFF_WC + (size_t)3*DMODEL*DMODEL*2)// 8 MiB
#define OFF_G   (OFF_WOB + (size_t)DMODEL*DMODEL*2) // 64 MiB (g, later t)
#define OFF_END (OFF_G + (size_t)MROWS*DMODEL*2)

extern "C" void kernel_launch(void* const* d_in, const int* in_sizes, int n_in,
                              void* d_out, int out_size, void* d_ws, size_t ws_size,
                              hipStream_t stream) {
    if (ws_size < OFF_END) return;  // refuse to run rather than corrupt adjacent memory

    const float* x    = (const float*)d_in[0];
    const float* Wq   = (const float*)d_in[1];
    const float* Wv   = (const float*)d_in[2];
    const float* Wg   = (const float*)d_in[3];
    const float* Wo   = (const float*)d_in[4];
    const float* beta = (const float*)d_in[5];
    const float* lnw  = (const float*)d_in[6];
    const float* lnb  = (const float*)d_in[7];

    char* ws = (char*)d_ws;
    ushort_t* xb  = (ushort_t*)(ws + OFF_XB);
    ushort_t* Wc  = (ushort_t*)(ws + OFF_WC);
    ushort_t* Wob = (ushort_t*)(ws + OFF_WOB);
    ushort_t* g   = (ushort_t*)(ws + OFF_G);
    float*    cf  = (float*)(ws + OFF_XB);   // overlays xb (dead after qvg GEMM)

    ushort_t* q = (ushort_t*)d_out;
    ushort_t* v = q + (size_t)MROWS * DMODEL;
    ushort_t* t = g;    // g slab reused by fused pass3 (element-wise aliasing)

    const int DD = DMODEL * DMODEL;

    // allow 128 KiB dynamic LDS (idempotent; return value intentionally ignored)
    (void)hipFuncSetAttribute((const void*)gemm8<3 * DMODEL, 0>,
                              hipFuncAttributeMaxDynamicSharedMemorySize, 131072);
    (void)hipFuncSetAttribute((const void*)gemm8<DMODEL, 1>,
                              hipFuncAttributeMaxDynamicSharedMemorySize, 131072);

    cast_f32_bf16<<<2048, 256, 0, stream>>>(x, xb, MROWS * DMODEL);
    cast_weights<<<dim3(256, 4), 256, 0, stream>>>(Wq, Wv, Wg, Wo,
                                                   Wc, Wc + DD, Wc + 2 * DD, Wob);

    // q,v,g = x @ [Wq;Wv;Wg]^T   (M=16384, N=6144, K=2048)
    gemm8<3 * DMODEL, 0><<<(MROWS / 256) * (3 * DMODEL / 256), 512, 131072, stream>>>(
        xb, Wc, q, v, g, nullptr);

    scan_pass1<<<dim3(NCH, NHEAD, BATCH), DHEAD, 0, stream>>>(v, beta, cf);
    scan_pass2<<<(BATCH * NHEAD * DHEAD) / 256, 256, 0, stream>>>(cf, beta);
    scan3_ln_gate<<<dim3(NCH, BATCH), 512, 0, stream>>>(v, q, g, beta, cf, lnw, lnb, t);

    // out = t @ Wo^T  (M=16384, N=2048, K=2048), fp32 output
    gemm8<DMODEL, 1><<<(MROWS / 256) * (DMODEL / 256), 512, 131072, stream>>>(
        t, Wob, nullptr, nullptr, nullptr, (float*)d_out);
}

// Round 10
// 608.692 us; speedup vs baseline: 1.1961x; 1.1046x over previous
//
#include <hip/hip_runtime.h>

// ---------- sizes (hardcoded for this problem) ----------
#define BATCH 4
#define SEQ   4096
#define DMODEL 2048
#define NHEAD 16
#define DHEAD 128
#define MROWS (BATCH*SEQ)          // 16384
#define LC    64                   // scan chunk length
#define NCH   (SEQ/LC)             // 64 chunks

typedef unsigned short ushort_t;
typedef __bf16 v8bf __attribute__((ext_vector_type(8)));
typedef float  f32x4 __attribute__((ext_vector_type(4)));

__device__ __forceinline__ float b2f(ushort_t h) {
    return __uint_as_float(((unsigned)h) << 16);
}
__device__ __forceinline__ ushort_t f2b(float f) {
    unsigned u = __float_as_uint(f);
    return (ushort_t)((u + 0x7fffu + ((u >> 16) & 1u)) >> 16);
}

// ---------- cast fp32 -> bf16 (8 elem/thread, 16B loads+stores) ----------
__global__ void cast_f32_bf16(const float* __restrict__ in, ushort_t* __restrict__ out, int n) {
    int i = (blockIdx.x * blockDim.x + threadIdx.x) * 8;
    const int stride = gridDim.x * blockDim.x * 8;
    for (; i < n; i += stride) {
        float4 a = *(const float4*)(in + i);
        float4 b = *(const float4*)(in + i + 4);
        ushort_t o[8] = {f2b(a.x), f2b(a.y), f2b(a.z), f2b(a.w),
                         f2b(b.x), f2b(b.y), f2b(b.z), f2b(b.w)};
        *(uint4*)(out + i) = *(const uint4*)o;
    }
}

// 4 weight matrices in one launch (blockIdx.y selects)
__global__ void cast_weights(const float* __restrict__ w0, const float* __restrict__ w1,
                             const float* __restrict__ w2, const float* __restrict__ w3,
                             ushort_t* __restrict__ o0, ushort_t* __restrict__ o1,
                             ushort_t* __restrict__ o2, ushort_t* __restrict__ o3) {
    const int wsel = blockIdx.y;
    const float* src = wsel == 0 ? w0 : wsel == 1 ? w1 : wsel == 2 ? w2 : w3;
    ushort_t* dst    = wsel == 0 ? o0 : wsel == 1 ? o1 : wsel == 2 ? o2 : o3;
    const int n = DMODEL * DMODEL;
    int i = (blockIdx.x * blockDim.x + threadIdx.x) * 8;
    const int stride = gridDim.x * blockDim.x * 8;
    for (; i < n; i += stride) {
        float4 a = *(const float4*)(src + i);
        float4 b = *(const float4*)(src + i + 4);
        ushort_t o[8] = {f2b(a.x), f2b(a.y), f2b(a.z), f2b(a.w),
                         f2b(b.x), f2b(b.y), f2b(b.z), f2b(b.w)};
        *(uint4*)(dst + i) = *(const uint4*)o;
    }
}

// ======== 256x256 bf16 GEMM: 16x16x32 MFMA, conflict-free LDS, pipelined body ========
// (round-7/9 verified: 357us qvg, MfmaUtil 54%, SQ_LDS_BANK_CONFLICT = 0)
// r8 lesson: keep 16x16x32 — 32x32x16 A-reads need 32 lanes x same slot over 32 rows,
// 8 slots/row -> unavoidable 4-way conflict (measured 3.78e7).

#define GLL(src, dstoff) __builtin_amdgcn_global_load_lds( \
    (const __attribute__((address_space(1))) void*)(src), \
    (__attribute__((address_space(3))) void*)((char*)lds + (dstoff)), 16, 0, 0)

#define STG_A(buf, half, kt) do { \
    GLL(pA + ((half) * 128 +  0) * (size_t)K + (kt), (buf) * 65536 + (half) * 16384 + wid * 1024); \
    GLL(pA + ((half) * 128 + 64) * (size_t)K + (kt), (buf) * 65536 + (half) * 16384 + wid * 1024 + 8192); } while (0)
#define STG_B(buf, half, kt) do { \
    GLL(pB + ((half) * 128 +  0) * (size_t)K + (kt), (buf) * 65536 + 32768 + (half) * 16384 + wid * 1024); \
    GLL(pB + ((half) * 128 + 64) * (size_t)K + (kt), (buf) * 65536 + 32768 + (half) * 16384 + wid * 1024 + 8192); } while (0)

// 4 ds_read_b128 into a named v8bf[4] set (offsets in ushort units; +1024 = 16 rows)
#define DSRD4(dst, off) do { \
    const ushort_t* _p = lds + (off); \
    dst[0] = *(const v8bf*)_p;          dst[1] = *(const v8bf*)(_p + 1024); \
    dst[2] = *(const v8bf*)(_p + 2048); dst[3] = *(const v8bf*)(_p + 3072); } while (0)

#define VMW(n) asm volatile("s_waitcnt vmcnt(" #n ")" ::: "memory")
#define BAR()  __builtin_amdgcn_s_barrier()

// prioritized 16-MFMA cluster; compiler inserts the (counted) lgkmcnt before first use
#define MM(mh, va, vb) do { \
    __builtin_amdgcn_s_setprio(1); \
    _Pragma("unroll") \
    for (int _m = 0; _m < 4; ++_m) \
        _Pragma("unroll") \
        for (int _n = 0; _n < 4; ++_n) \
            acc[(mh) * 4 + _m][_n] = __builtin_amdgcn_mfma_f32_16x16x32_bf16( \
                va[_m], vb[_n], acc[(mh) * 4 + _m][_n], 0, 0, 0); \
    __builtin_amdgcn_s_setprio(0); \
} while (0)

template<int N, int EPI>
__global__ __launch_bounds__(512, 2) void gemm8(const ushort_t* __restrict__ A,
                                                const ushort_t* __restrict__ Bm,
                                                ushort_t* __restrict__ o0,
                                                ushort_t* __restrict__ o1,
                                                ushort_t* __restrict__ o2,
                                                float* __restrict__ of) {
    constexpr int K  = DMODEL;
    constexpr int NT = K / 64;           // 32 K-tiles
    constexpr int NBN = N / 256;
    constexpr int NWG = (MROWS / 256) * NBN;
    extern __shared__ ushort_t lds[];    // 65536 ushorts = 128 KiB

    // XCD-bijective swizzle (NWG % 8 == 0 for both instantiations)
    int wg = blockIdx.x;
    wg = (wg & 7) * (NWG / 8) + (wg >> 3);
    const int tm = (wg / NBN) * 256;
    const int tn = (wg % NBN) * 256;

    const int tid  = threadIdx.x;
    const int lane = tid & 63;
    const int wid  = tid >> 6;           // 8 waves
    const int wr   = wid >> 2;           // 0..1 (M half)
    const int wc   = wid & 3;            // 0..3 (N quarter)

    // ---- staging source base (per-lane, pre-swizzled; dest stays linear) ----
    const int rs = wid * 8 + (lane >> 3);
    const int cs = ((lane & 7) ^ ((lane >> 3) & 7)) * 8;
    const ushort_t* pA = A  + (size_t)(tm + rs) * K + cs;
    const ushort_t* pB = Bm + (size_t)(tn + rs) * K + cs;

    // ---- fragment ds_read bases (ushort units) ----
    const int q  = lane >> 4;
    const int l4 = lane & 15;
    const int sx = l4 & 7;
    const int abase0 = (wr * 128 + l4) * 64 + ((q ^ sx)) * 8;
    const int abase1 = (wr * 128 + l4) * 64 + (((4 + q) ^ sx)) * 8;
    const int bbase0 = 16384 + (wc * 64 + l4) * 64 + ((q ^ sx)) * 8;
    const int bbase1 = 16384 + (wc * 64 + l4) * 64 + (((4 + q) ^ sx)) * 8;

    f32x4 acc[8][4] = {};
    v8bf a00[4], a10[4], a01[4], a11[4], b0[4], b1[4];

    // ---- prologue: stage tile 0 fully into buf0 (8 loads), no wait yet ----
    STG_A(0, 0, 0); STG_A(0, 1, 0); STG_B(0, 0, 0); STG_B(0, 1, 0);

    // ---- main loop: pipelined K-tile body; vmcnt(2) + 2 barriers per K-tile ----
    for (int t = 0; t < NT - 1; ++t) {
        const int cur = t & 1, nxt = cur ^ 1;
        const int ktn = (t + 1) * 64;
        const int cb = cur * 32768;
        STG_A(nxt, 0, ktn);
        VMW(2);
        BAR();
        DSRD4(a00, cb + abase0);          // mh0 kk0
        DSRD4(b0,  cb + bbase0);          // kk0
        DSRD4(a10, cb + abase0 + 4096);   // mh1 kk0
        MM(0, a00, b0);
        STG_A(nxt, 1, ktn);
        DSRD4(a01, cb + abase1);          // mh0 kk1
        DSRD4(b1,  cb + bbase1);          // kk1
        MM(1, a10, b0);
        STG_B(nxt, 0, ktn);
        DSRD4(a11, cb + abase1 + 4096);   // mh1 kk1
        MM(0, a01, b1);
        STG_B(nxt, 1, ktn);
        MM(1, a11, b1);
        BAR();
    }
    // ---- peeled last tile: no staging; full drain ----
    {
        const int cb = ((NT - 1) & 1) * 32768;
        VMW(0);
        BAR();
        DSRD4(a00, cb + abase0);
        DSRD4(b0,  cb + bbase0);
        DSRD4(a10, cb + abase0 + 4096);
        MM(0, a00, b0);
        DSRD4(a01, cb + abase1);
        DSRD4(b1,  cb + bbase1);
        MM(1, a10, b0);
        DSRD4(a11, cb + abase1 + 4096);
        MM(0, a01, b1);
        MM(1, a11, b1);
    }

    // ---- epilogue: C/D layout col=lane&15, row=(lane>>4)*4+j ----
    const int cr = (lane >> 4) * 4;
    const int cc = lane & 15;
    if constexpr (EPI == 0) {
        ushort_t* out = (tn < 2048) ? o0 : (tn < 4096 ? o1 : o2);
        const int nc0 = tn & 2047;
#pragma unroll
        for (int m = 0; m < 8; ++m) {
            const int r0 = tm + wr * 128 + m * 16 + cr;
#pragma unroll
            for (int n = 0; n < 4; ++n) {
                const int c = nc0 + wc * 64 + n * 16 + cc;
#pragma unroll
                for (int j = 0; j < 4; ++j)
                    out[(size_t)(r0 + j) * 2048 + c] = f2b(acc[m][n][j]);
            }
        }
    } else {
#pragma unroll
        for (int m = 0; m < 8; ++m) {
            const int r0 = tm + wr * 128 + m * 16 + cr;
#pragma unroll
            for (int n = 0; n < 4; ++n) {
                const int c = tn + wc * 64 + n * 16 + cc;
#pragma unroll
                for (int j = 0; j < 4; ++j)
                    of[(size_t)(r0 + j) * N + c] = acc[m][n][j];
            }
        }
    }
}

// ---------- retention scan (state_t = lam*state_{t-1} + v_t), chunked ----------
// pass1: per-chunk (LC=64) local scan final -> cf[b][h][chunk][dh]
// grid (NCH, BATCH) x 512 threads; thread = 4 channels of one head (uint2 loads).
__global__ __launch_bounds__(512) void scan_pass1(const ushort_t* __restrict__ v,
                                                  const float* __restrict__ beta,
                                                  float* __restrict__ cf) {
    const int chunk = blockIdx.x, b = blockIdx.y;
    const int tid = threadIdx.x;
    const int h   = tid >> 5;
    const int c32 = (tid & 31) << 2;
    const float lam = 1.f / (1.f + __expf(-beta[h]));
    size_t idx = (size_t)(b * SEQ + chunk * LC) * DMODEL + (h << 7) + c32;
    float s0 = 0.f, s1 = 0.f, s2 = 0.f, s3 = 0.f;
#pragma unroll 4
    for (int l = 0; l < LC; ++l) {
        const uint2 vv = *(const uint2*)(v + idx);
        s0 = fmaf(s0, lam, b2f((ushort_t)(vv.x & 0xffff)));
        s1 = fmaf(s1, lam, b2f((ushort_t)(vv.x >> 16)));
        s2 = fmaf(s2, lam, b2f((ushort_t)(vv.y & 0xffff)));
        s3 = fmaf(s3, lam, b2f((ushort_t)(vv.y >> 16)));
        idx += DMODEL;
    }
    float* o = cf + ((size_t)(b * NHEAD + h) * NCH + chunk) * DHEAD + c32;
    o[0] = s0; o[1] = s1; o[2] = s2; o[3] = s3;
}

// pass2: in-place exclusive scan over chunks
__global__ void scan_pass2(float* __restrict__ cf, const float* __restrict__ beta) {
    const int t = blockIdx.x * blockDim.x + threadIdx.x;   // B*H*Dh = 8192
    const int dh = t & 127;
    const int bh = t >> 7;          // b*16 + h
    const int h = bh & 15;
    const float lam = 1.f / (1.f + __expf(-beta[h]));
    float lamLc = lam;
#pragma unroll
    for (int i = 0; i < 6; ++i) lamLc *= lamLc;   // lam^64
    float carry = 0.f;
    for (int c = 0; c < NCH; ++c) {
        const size_t i = ((size_t)bh * NCH + c) * DHEAD + dh;
        const float val = cf[i];
        cf[i] = carry;
        carry = fmaf(carry, lamLc, val);
    }
}

// ---- fused pass3: scan + y=q*state + rowwise LayerNorm + SiLU gate -> t (bf16) ----
// grid (NCH, BATCH) = 256 blocks x 512 threads; thread handles 4 channels of one head.
// Rows processed in groups of 4: all 12 loads issued together (4x MLP), 4 reductions
// share ONE barrier via parity-double-buffered red[2][4][16]. (r9 post-mortem: the
// 2-barrier-per-row version was latency-bound at ~120us; this targets ~15-25us.)
// Safety of single barrier: a buffer's reads (iter g, after bar g) and its next
// overwrite (iter g+2, after bar g+1) are separated by barrier g+1.
// t may alias g element-for-element (g[idx] read before t[idx] written, same thread).
__global__ __launch_bounds__(512) void scan3_ln_gate(const ushort_t* __restrict__ v,
                                                     const ushort_t* __restrict__ q,
                                                     const ushort_t* gi,
                                                     const float* __restrict__ beta,
                                                     const float* __restrict__ cf,
                                                     const float* __restrict__ lnw,
                                                     const float* __restrict__ lnb,
                                                     ushort_t* t) {
    const int chunk = blockIdx.x;      // 64
    const int b     = blockIdx.y;      // 4
    const int tid   = threadIdx.x;     // 512
    const int h     = tid >> 5;        // 16 heads, 32 threads each
    const int c32   = (tid & 31) << 2;
    const int col   = (h << 7) + c32;
    const float lam = 1.f / (1.f + __expf(-beta[h]));

    float s0, s1, s2, s3;
    {
        const float* c0 = cf + ((size_t)(b * NHEAD + h) * NCH + chunk) * DHEAD + c32;
        s0 = c0[0]; s1 = c0[1]; s2 = c0[2]; s3 = c0[3];
    }
    const float4 w = *(const float4*)(lnw + col);
    const float4 e = *(const float4*)(lnb + col);

    __shared__ float red[2][4][16];    // [parity][row-in-group][wave(0..7) | 8+wave]
    const int wv = tid >> 6;
    const bool l0 = (tid & 63) == 0;

    size_t idx = (size_t)(b * SEQ + chunk * LC) * DMODEL + col;

    for (int gidx = 0; gidx < LC / 4; ++gidx) {
        const int p = gidx & 1;
        uint2 vv[4], qv[4], gv[4];
#pragma unroll
        for (int r = 0; r < 4; ++r) {
            vv[r] = *(const uint2*)(v  + idx + (size_t)r * DMODEL);
            qv[r] = *(const uint2*)(q  + idx + (size_t)r * DMODEL);
            gv[r] = *(const uint2*)(gi + idx + (size_t)r * DMODEL);
        }
        float y[4][4];
#pragma unroll
        for (int r = 0; r < 4; ++r) {
            s0 = fmaf(s0, lam, b2f((ushort_t)(vv[r].x & 0xffff)));
            s1 = fmaf(s1, lam, b2f((ushort_t)(vv[r].x >> 16)));
            s2 = fmaf(s2, lam, b2f((ushort_t)(vv[r].y & 0xffff)));
            s3 = fmaf(s3, lam, b2f((ushort_t)(vv[r].y >> 16)));
            y[r][0] = b2f((ushort_t)(qv[r].x & 0xffff)) * s0;
            y[r][1] = b2f((ushort_t)(qv[r].x >> 16)) * s1;
            y[r][2] = b2f((ushort_t)(qv[r].y & 0xffff)) * s2;
            y[r][3] = b2f((ushort_t)(qv[r].y >> 16)) * s3;
        }
#pragma unroll
        for (int r = 0; r < 4; ++r) {
            float ps  = y[r][0] + y[r][1] + y[r][2] + y[r][3];
            float pss = y[r][0] * y[r][0] + y[r][1] * y[r][1]
                      + y[r][2] * y[r][2] + y[r][3] * y[r][3];
#pragma unroll
            for (int o = 32; o > 0; o >>= 1) {
                ps  += __shfl_down(ps, o);
                pss += __shfl_down(pss, o);
            }
            if (l0) { red[p][r][wv] = ps; red[p][r][8 + wv] = pss; }
        }
        __syncthreads();
#pragma unroll
        for (int r = 0; r < 4; ++r) {
            float S = 0.f, SS = 0.f;
#pragma unroll
            for (int k = 0; k < 8; ++k) { S += red[p][r][k]; SS += red[p][r][8 + k]; }
            const float mu  = S * (1.f / DMODEL);
            const float var = SS * (1.f / DMODEL) - mu * mu;
            const float rsr = rsqrtf(var + 1e-5f);
            const float g0 = b2f((ushort_t)(gv[r].x & 0xffff));
            const float g1 = b2f((ushort_t)(gv[r].x >> 16));
            const float g2 = b2f((ushort_t)(gv[r].y & 0xffff));
            const float g3 = b2f((ushort_t)(gv[r].y >> 16));
            ushort_t o[4];
            o[0] = f2b(((y[r][0] - mu) * rsr * w.x + e.x) * (g0 / (1.f + __expf(-g0))));
            o[1] = f2b(((y[r][1] - mu) * rsr * w.y + e.y) * (g1 / (1.f + __expf(-g1))));
            o[2] = f2b(((y[r][2] - mu) * rsr * w.z + e.z) * (g2 / (1.f + __expf(-g2))));
            o[3] = f2b(((y[r][3] - mu) * rsr * w.w + e.w) * (g3 / (1.f + __expf(-g3))));
            *(uint2*)(t + idx + (size_t)r * DMODEL) = *(const uint2*)o;
        }
        idx += (size_t)4 * DMODEL;
    }
}

// ---------- workspace layout (bytes) — TOTAL 160 MiB ----------
#define OFF_XB  ((size_t)0)                         // 64 MiB (xb; cf after qvg)
#define OFF_WC  (OFF_XB + (size_t)MROWS*DMODEL*2)   // 24 MiB
#define OFF_WOB (OFF_WC + (size_t)3*DMODEL*DMODEL*2)// 8 MiB
#define OFF_G   (OFF_WOB + (size_t)DMODEL*DMODEL*2) // 64 MiB (g, later t)
#define OFF_END (OFF_G + (size_t)MROWS*DMODEL*2)

extern "C" void kernel_launch(void* const* d_in, const int* in_sizes, int n_in,
                              void* d_out, int out_size, void* d_ws, size_t ws_size,
                              hipStream_t stream) {
    if (ws_size < OFF_END) return;  // refuse to run rather than corrupt adjacent memory

    const float* x    = (const float*)d_in[0];
    const float* Wq   = (const float*)d_in[1];
    const float* Wv   = (const float*)d_in[2];
    const float* Wg   = (const float*)d_in[3];
    const float* Wo   = (const float*)d_in[4];
    const float* beta = (const float*)d_in[5];
    const float* lnw  = (const float*)d_in[6];
    const float* lnb  = (const float*)d_in[7];

    char* ws = (char*)d_ws;
    ushort_t* xb  = (ushort_t*)(ws + OFF_XB);
    ushort_t* Wc  = (ushort_t*)(ws + OFF_WC);
    ushort_t* Wob = (ushort_t*)(ws + OFF_WOB);
    ushort_t* g   = (ushort_t*)(ws + OFF_G);
    float*    cf  = (float*)(ws + OFF_XB);   // overlays xb (dead after qvg GEMM)

    ushort_t* q = (ushort_t*)d_out;
    ushort_t* v = q + (size_t)MROWS * DMODEL;
    ushort_t* t = g;    // g slab reused by fused pass3 (element-wise aliasing)

    const int DD = DMODEL * DMODEL;

    // allow 128 KiB dynamic LDS (idempotent; return value intentionally ignored)
    (void)hipFuncSetAttribute((const void*)gemm8<3 * DMODEL, 0>,
                              hipFuncAttributeMaxDynamicSharedMemorySize, 131072);
    (void)hipFuncSetAttribute((const void*)gemm8<DMODEL, 1>,
                              hipFuncAttributeMaxDynamicSharedMemorySize, 131072);

    cast_f32_bf16<<<2048, 256, 0, stream>>>(x, xb, MROWS * DMODEL);
    cast_weights<<<dim3(256, 4), 256, 0, stream>>>(Wq, Wv, Wg, Wo,
                                                   Wc, Wc + DD, Wc + 2 * DD, Wob);

    // q,v,g = x @ [Wq;Wv;Wg]^T   (M=16384, N=6144, K=2048)
    gemm8<3 * DMODEL, 0><<<(MROWS / 256) * (3 * DMODEL / 256), 512, 131072, stream>>>(
        xb, Wc, q, v, g, nullptr);

    scan_pass1<<<dim3(NCH, BATCH), 512, 0, stream>>>(v, beta, cf);
    scan_pass2<<<(BATCH * NHEAD * DHEAD) / 256, 256, 0, stream>>>(cf, beta);
    scan3_ln_gate<<<dim3(NCH, BATCH), 512, 0, stream>>>(v, q, g, beta, cf, lnw, lnb, t);

    // out = t @ Wo^T  (M=16384, N=2048, K=2048), fp32 output
    gemm8<DMODEL, 1><<<(MROWS / 256) * (DMODEL / 256), 512, 131072, stream>>>(
        t, Wob, nullptr, nullptr, nullptr, (float*)d_out);
}